// Round 8
// baseline (220.139 us; speedup 1.0000x reference)
//
#include <hip/hip_runtime.h>

static inline int ceil_div(int a, int b){ return (a+b-1)/b; }
static inline size_t align_up(size_t x, size_t a){ return (x + a - 1) / a * a; }

typedef __bf16 bf16x8 __attribute__((ext_vector_type(8)));
typedef float  f32x4  __attribute__((ext_vector_type(4)));

static __device__ inline unsigned short f2bf(float f){
    unsigned int u = __float_as_uint(f);
    unsigned int lsb = (u >> 16) & 1u;
    u += 0x7FFFu + lsb;
    return (unsigned short)(u >> 16);
}
static __device__ inline float bf2f(unsigned short b){
    return __uint_as_float(((unsigned int)b) << 16);
}
static __device__ inline unsigned int packbf(float a, float b){
    return (unsigned int)f2bf(a) | ((unsigned int)f2bf(b) << 16);
}

// async 16B global->LDS (wave-uniform LDS base + lane*16 layout)
static __device__ inline void gload_lds16(const void* g, void* l) {
    __builtin_amdgcn_global_load_lds(
        (const __attribute__((address_space(1))) unsigned int*)g,
        (__attribute__((address_space(3))) unsigned int*)l, 16, 0, 0);
}

// Bt[o][kk] bf16: kk<1024 -> W[r=kk>>7][i=kk&127][o]; kk>=1024 -> root[kk-1024][o]
__global__ void compute_Bt_kernel(const float* __restrict__ comp, const float* __restrict__ basis,
                                  const float* __restrict__ root, unsigned short* __restrict__ Bt,
                                  int B) {
    int idx = blockIdx.x*blockDim.x + threadIdx.x;
    if (idx >= 128*1152) return;
    int o = idx / 1152, kk = idx - o*1152;
    float val;
    if (kk < 1024) {
        int r = kk >> 7, i = kk & 127;
        val = 0.f;
        for (int b = 0; b < B; ++b)
            val += comp[r*B+b] * basis[((size_t)b*128 + i)*128 + o];
    } else {
        val = root[(size_t)(kk-1024)*128 + o];
    }
    Bt[idx] = f2bf(val);
}

__global__ void count_kernel(const int* __restrict__ dst, const int* __restrict__ et,
                             int* __restrict__ cnt, int E, int R) {
    int e = blockIdx.x*blockDim.x + threadIdx.x;
    if (e >= E) return;
    atomicAdd(&cnt[(size_t)dst[e]*R + et[e]], 1);
}

__global__ __launch_bounds__(256)
void scan_block_kernel(const int* __restrict__ in, int* __restrict__ out,
                       int* __restrict__ bsums, int n) {
    __shared__ int tsum[256];
    int t = threadIdx.x;
    int idx0 = blockIdx.x*1024 + t*4;
    int v0 = (idx0+0 < n) ? in[idx0+0] : 0;
    int v1 = (idx0+1 < n) ? in[idx0+1] : 0;
    int v2 = (idx0+2 < n) ? in[idx0+2] : 0;
    int v3 = (idx0+3 < n) ? in[idx0+3] : 0;
    int s = v0+v1+v2+v3;
    tsum[t] = s; __syncthreads();
    for (int off = 1; off < 256; off <<= 1) {
        int x = (t >= off) ? tsum[t-off] : 0;
        __syncthreads();
        tsum[t] += x;
        __syncthreads();
    }
    int run = tsum[t] - s;
    if (idx0+0 < n) out[idx0+0] = run; run += v0;
    if (idx0+1 < n) out[idx0+1] = run; run += v1;
    if (idx0+2 < n) out[idx0+2] = run; run += v2;
    if (idx0+3 < n) out[idx0+3] = run;
    if (bsums && t == 255) bsums[blockIdx.x] = tsum[255];
}

__global__ void scan_add_kernel(int* __restrict__ out, const int* __restrict__ bs,
                                int n, int total) {
    int i = blockIdx.x*blockDim.x + threadIdx.x;
    if (i < n) out[i] += bs[i >> 10];
    if (i == 0) out[n] = total;
}

// slot = atomicAdd(&offsets[bin],1): offsets mutates into shifted-by-one bounds.
__global__ void fill_kernel(const int* __restrict__ src, const int* __restrict__ dst,
                            const int* __restrict__ et, int* __restrict__ offsets,
                            int* __restrict__ slot_src, int E, int R) {
    int e = blockIdx.x*blockDim.x + threadIdx.x;
    if (e >= E) return;
    int bin = dst[e]*R + et[e];
    int slot = atomicAdd(&offsets[bin], 1);
    slot_src[slot] = src[e];
}

// x (f32) -> compact bf16 buffer Xb [N][128] (u32 pairs)
__global__ __launch_bounds__(256)
void xb_kernel(const float* __restrict__ x, unsigned int* __restrict__ Xb2, int N) {
    int t = blockIdx.x*blockDim.x + threadIdx.x;
    int n = t >> 6;
    if (n >= N) return;
    int l = t & 63;
    float2 v = reinterpret_cast<const float2*>(x + (size_t)n*128)[l];
    Xb2[(size_t)n*64 + l] = packbf(v.x, v.y);
}

// 4 waves per node, 2 bins per wave. Bounds shifted-by-one: bin b = [off[b-1], off[b]).
// Masked always-4-wide gather: all slot+row loads of an iteration are independent
// (clamped indices + wave-uniform zero masking), so a typical wave (<=4 edges) has
// exactly one bounds->slots->rows->store chain.
__global__ __launch_bounds__(256)
void aggregate_kernel(const int* __restrict__ offsets, const int* __restrict__ slot_src,
                      const unsigned int* __restrict__ Xb2, unsigned int* __restrict__ Mc2,
                      int N) {
    int gw = (int)((blockIdx.x*blockDim.x + threadIdx.x) >> 6);
    int node = gw >> 2, part = gw & 3;
    if (node >= N) return;
    int l = threadIdx.x & 63;
    int base = node*8 + part*2;
    int lo   = (base == 0) ? 0 : offsets[base-1];
    int bmid = offsets[base];
    int hi   = offsets[base+1];

    float ax0=0.f, ay0=0.f, ax1=0.f, ay1=0.f;

#define ACC2(E_, U_) { \
    float vx_ = bf2f((unsigned short)((U_) & 0xFFFFu)); \
    float vy_ = bf2f((unsigned short)((U_) >> 16)); \
    if ((E_) < bmid) { ax0 += vx_; ay0 += vy_; } \
    else             { ax1 += vx_; ay1 += vy_; } }

    for (int e = lo; e < hi; e += 4) {
        int hm = hi - 1;
        int i1 = (e+1 < hm) ? e+1 : hm;
        int i2 = (e+2 < hm) ? e+2 : hm;
        int i3 = (e+3 < hm) ? e+3 : hm;
        int s0 = slot_src[e];
        int s1 = slot_src[i1];
        int s2 = slot_src[i2];
        int s3 = slot_src[i3];
        unsigned int u0 = Xb2[(size_t)s0*64 + l];
        unsigned int u1 = Xb2[(size_t)s1*64 + l];
        unsigned int u2 = Xb2[(size_t)s2*64 + l];
        unsigned int u3 = Xb2[(size_t)s3*64 + l];
        if (e+1 >= hi) u1 = 0u;        // wave-uniform masks
        if (e+2 >= hi) u2 = 0u;
        if (e+3 >= hi) u3 = 0u;
        ACC2(e+0, u0) ACC2(e+1, u1) ACC2(e+2, u2) ACC2(e+3, u3)
    }
#undef ACC2

    unsigned int* Mrow = Mc2 + (size_t)node*512;
    float i0 = 1.f/fmaxf((float)(bmid-lo), 1.f);
    float i1 = 1.f/fmaxf((float)(hi-bmid), 1.f);
    __builtin_nontemporal_store(packbf(ax0*i0, ay0*i0), &Mrow[(2*part+0)*64 + l]);
    __builtin_nontemporal_store(packbf(ax1*i1, ay1*i1), &Mrow[(2*part+1)*64 + l]);
}

// h(bf16)[Mpad][128] = relu( [Mc | Xb] @ Bt^T + bias )
// m97-style: BM=64 x BN=128 tile, BK=64, single-buffered LDS, global_load_lds(16B),
// XOR-swizzled source+read (linear LDS dest). 4 waves: rg=wid&1 (32 rows), cg=wid>>1 (64 cols).
__global__ __launch_bounds__(256)
void mfma_gemm_kernel(const unsigned short* __restrict__ Mc,
                      const unsigned short* __restrict__ Xb,
                      const unsigned short* __restrict__ Btc,
                      const float* __restrict__ bias,
                      unsigned short* __restrict__ h) {
    __shared__ char ldsA[64*128];    // 8 KB
    __shared__ char ldsB[128*128];   // 16 KB

    int tid  = threadIdx.x;
    int lane = tid & 63;
    int wid  = tid >> 6;
    int rg = wid & 1, cg = wid >> 1;
    int fr = lane & 15, kb = lane >> 4;
    long m0 = (long)blockIdx.x * 64;

    int lrow8 = lane >> 3;            // 0..7 row within an issue
    int lcb   = (lane & 7) * 16;      // 16B slot within 128B row

    f32x4 acc[2][4];
    #pragma unroll
    for (int mf = 0; mf < 2; ++mf)
        #pragma unroll
        for (int nf = 0; nf < 4; ++nf) acc[mf][nf] = f32x4{0.f,0.f,0.f,0.f};

    const char* McB = (const char*)Mc;
    const char* XbB = (const char*)Xb;
    const char* BtB = (const char*)Btc;

    for (int t = 0; t < 18; ++t) {
        #pragma unroll
        for (int i = 0; i < 2; ++i) {
            int row = wid*16 + i*8 + lrow8;
            int sw  = lcb ^ ((row & 7) << 4);
            const char* g = (t < 16)
                ? McB + (size_t)(m0 + row)*2048 + t*128 + sw
                : XbB + (size_t)(m0 + row)*256 + (t-16)*128 + sw;
            gload_lds16(g, &ldsA[wid*2048 + i*1024 + lane*16]);
        }
        #pragma unroll
        for (int i = 0; i < 4; ++i) {
            int col = wid*32 + i*8 + lrow8;
            int sw  = lcb ^ ((col & 7) << 4);
            const char* g = BtB + (size_t)col*2304 + t*128 + sw;
            gload_lds16(g, &ldsB[wid*4096 + i*1024 + lane*16]);
        }
        __syncthreads();

        bf16x8 af[2][2], bf[4][2];
        #pragma unroll
        for (int mf = 0; mf < 2; ++mf) {
            int row = rg*32 + mf*16 + fr;
            #pragma unroll
            for (int kk = 0; kk < 2; ++kk) {
                int byte = row*128 + ((kk*64 + kb*16) ^ ((row & 7) << 4));
                af[mf][kk] = *reinterpret_cast<const bf16x8*>(&ldsA[byte]);
            }
        }
        #pragma unroll
        for (int nf = 0; nf < 4; ++nf) {
            int col = cg*64 + nf*16 + fr;
            #pragma unroll
            for (int kk = 0; kk < 2; ++kk) {
                int byte = col*128 + ((kk*64 + kb*16) ^ ((col & 7) << 4));
                bf[nf][kk] = *reinterpret_cast<const bf16x8*>(&ldsB[byte]);
            }
        }
        #pragma unroll
        for (int kk = 0; kk < 2; ++kk)
            #pragma unroll
            for (int mf = 0; mf < 2; ++mf)
                #pragma unroll
                for (int nf = 0; nf < 4; ++nf)
                    acc[mf][nf] = __builtin_amdgcn_mfma_f32_16x16x32_bf16(
                        af[mf][kk], bf[nf][kk], acc[mf][nf], 0, 0, 0);
        __syncthreads();
    }

    float bb[4];
    #pragma unroll
    for (int nf = 0; nf < 4; ++nf) bb[nf] = bias[cg*64 + nf*16 + fr];

    #pragma unroll
    for (int mf = 0; mf < 2; ++mf)
        #pragma unroll
        for (int q = 0; q < 4; ++q) {
            long r = m0 + rg*32 + mf*16 + kb*4 + q;
            unsigned short* hr = h + (size_t)r*128 + cg*64;
            #pragma unroll
            for (int nf = 0; nf < 4; ++nf)
                hr[nf*16 + fr] = f2bf(fmaxf(acc[mf][nf][q] + bb[nf], 0.f));
        }
}

// Fused: per-graph row-range (binary search on sorted batch) -> mean pool -> FC.
__global__ __launch_bounds__(512)
void pool_fc_kernel(const unsigned int* __restrict__ h2, const int* __restrict__ batch,
                    const float* __restrict__ fw, const float* __restrict__ fb,
                    float* __restrict__ out, int N, int C) {
    int g = blockIdx.x;
    int t = threadIdx.x;
    int lo = 0, hi = N;
    while (lo < hi) { int mid = (lo+hi) >> 1; if (batch[mid] < g) lo = mid+1; else hi = mid; }
    int s0 = lo;
    hi = N;
    while (lo < hi) { int mid = (lo+hi) >> 1; if (batch[mid] < g+1) lo = mid+1; else hi = mid; }
    int s1 = lo;

    int d2 = t & 63;
    float ax = 0.f, ay = 0.f;
    for (int row = s0 + (t >> 6); row < s1; row += 8) {
        unsigned int u = h2[(size_t)row*64 + d2];
        ax += bf2f((unsigned short)(u & 0xFFFFu));
        ay += bf2f((unsigned short)(u >> 16));
    }
    __shared__ float ps[128];
    if (t < 128) ps[t] = 0.f;
    __syncthreads();
    atomicAdd(&ps[2*d2],   ax);
    atomicAdd(&ps[2*d2+1], ay);
    __syncthreads();
    if (t < C) {
        float inv = 1.f / fmaxf((float)(s1 - s0), 1.f);
        float s = 0.f;
        #pragma unroll 4
        for (int k = 0; k < 128; ++k) s += ps[k] * fw[(size_t)k*C + t];
        out[(size_t)g*C + t] = s * inv + fb[t];
    }
}

extern "C" void kernel_launch(void* const* d_in, const int* in_sizes, int n_in,
                              void* d_out, int out_size, void* d_ws, size_t ws_size,
                              hipStream_t stream) {
    const float* x       = (const float*)d_in[0];
    const int*   eindex  = (const int*)  d_in[1];
    const int*   etype   = (const int*)  d_in[2];
    const int*   batch   = (const int*)  d_in[4];
    const float* basis   = (const float*)d_in[6];
    const float* comp    = (const float*)d_in[7];
    const float* root    = (const float*)d_in[8];
    const float* bias    = (const float*)d_in[9];
    const float* fc_w    = (const float*)d_in[10];
    const float* fc_b    = (const float*)d_in[11];

    int N  = in_sizes[4];          // 50000
    int E  = in_sizes[2];          // 600000
    int C  = in_sizes[11];         // 16
    int G  = out_size / C;         // 64
    int IO = in_sizes[8];          // 16384
    int B  = in_sizes[6] / IO;     // 4
    int R  = in_sizes[7] / B;      // 8
    int NR = N * R;
    int MB = ceil_div(N, 64);      // 64-row GEMM blocks
    int Mpad = MB * 64;

    const int* src = eindex;
    const int* dst = eindex + E;

    // ---- workspace layout (~134 MB) ----
    char* base = (char*)d_ws;
    size_t off = 0;
    auto alloc = [&](size_t bytes) -> char* {
        char* p = base + off;
        off = align_up(off + bytes, 256);
        return p;
    };
    unsigned short* Bt  = (unsigned short*)alloc(sizeof(unsigned short)*128*1152);
    int*   cnt      = (int*)  alloc(sizeof(int)*(size_t)NR);
    int*   offsets  = (int*)  alloc(sizeof(int)*((size_t)NR+1));
    int*   bsums    = (int*)  alloc(sizeof(int)*1024);
    int*   slot_src = (int*)  alloc(sizeof(int)*(size_t)E);
    unsigned short* h  = (unsigned short*)alloc(sizeof(unsigned short)*(size_t)Mpad*128);
    unsigned short* Xb = (unsigned short*)alloc(sizeof(unsigned short)*(size_t)Mpad*128);
    unsigned short* Mc = (unsigned short*)alloc(sizeof(unsigned short)*(size_t)Mpad*1024);

    // ---- pipeline ----
    hipMemsetAsync(cnt, 0, sizeof(int)*(size_t)NR, stream);
    compute_Bt_kernel<<<ceil_div(128*1152,256),256,0,stream>>>(comp, basis, root, Bt, B);
    count_kernel<<<ceil_div(E,256),256,0,stream>>>(dst, etype, cnt, E, R);

    int nb = ceil_div(NR, 1024);
    scan_block_kernel<<<nb,256,0,stream>>>(cnt, offsets, bsums, NR);
    scan_block_kernel<<<1,256,0,stream>>>(bsums, bsums, nullptr, nb);
    scan_add_kernel<<<ceil_div(NR,256),256,0,stream>>>(offsets, bsums, NR, E);

    fill_kernel<<<ceil_div(E,256),256,0,stream>>>(src, dst, etype, offsets, slot_src, E, R);

    xb_kernel<<<ceil_div(N*64,256),256,0,stream>>>(x, (unsigned int*)Xb, N);
    aggregate_kernel<<<ceil_div(N*4*64,256),256,0,stream>>>(offsets, slot_src,
                                                            (const unsigned int*)Xb,
                                                            (unsigned int*)Mc, N);

    mfma_gemm_kernel<<<MB,256,0,stream>>>(Mc, Xb, Bt, bias, h);

    pool_fc_kernel<<<G,512,0,stream>>>((const unsigned int*)h, batch, fc_w, fc_b,
                                       (float*)d_out, N, C);
}